// Round 1
// baseline (305.660 us; speedup 1.0000x reference)
//
#include <hip/hip_runtime.h>

// Fixed-point quantize to (int_bits=6, frac_bits=10):
// round-half-even to 2^-10 grid, clamp to [-64, 64 - 2^-10].
// rintf == v_rndne_f32 (nearest-even) matches jnp.round semantics.
__device__ __forceinline__ float fpq10(float x) {
    float r = rintf(x * 1024.0f) * 0.0009765625f;  // /1024 exact (pow2)
    r = fmaxf(r, -64.0f);
    r = fminf(r, 63.9990234375f);
    return r;
}

__global__ __launch_bounds__(256) void qsh_kernel(const float* __restrict__ in,
                                                  float* __restrict__ out,
                                                  int n) {
    int i = blockIdx.x * blockDim.x + threadIdx.x;
    if (i >= n) return;

    size_t b = 3u * (size_t)i;
    float u = in[b + 0];
    float v = in[b + 1];
    float w = in[b + 2];

    // u*2-1 may contract to fma; u*2 is exact so result is bit-identical either way.
    float x = fpq10(u * 2.0f - 1.0f);
    float y = fpq10(v * 2.0f - 1.0f);
    float z = fpq10(w * 2.0f - 1.0f);
    float xy = fpq10(x * y);
    float xz = fpq10(x * z);
    float yz = fpq10(y * z);
    float x2 = fpq10(x * x);
    float y2 = fpq10(y * y);
    float z2 = fpq10(z * z);

    // qc(c) = fpq(float32(c)) precomputed (k/1024 values, hand-verified):
    const float C0  = 0.2822265625f;   // 0.28209479177387814 -> 289/1024
    const float C1  = 0.48828125f;     // 0.48860251190291987 -> 500/1024
    const float C2  = 1.0927734375f;   // 1.0925484305920792  -> 1119/1024
    const float C3  = 0.9462890625f;   // 0.94617469575756    -> 969/1024
    const float C4  = 0.3154296875f;   // 0.31539156525252    -> 323/1024
    const float C5  = 0.5458984375f;   // 0.5462742152960396  -> 559/1024
    const float C6  = 0.58984375f;     // 0.5900435899266435  -> 604/1024
    const float C7  = 2.890625f;       // 2.890611442640554   -> 2960/1024
    const float C8  = 0.45703125f;     // 0.4570457994644657  -> 468/1024
    const float C9  = 0.373046875f;    // 0.3731763325901154  -> 382/1024
    const float C10 = 1.4453125f;      // 1.445305721320277   -> 1480/1024

    // qf() on already-quantized values is mathematically identity, but keep
    // the faithful structure (cheap; kernel is memory-bound anyway).
    float o0  = C0;
    float o1  = fpq10(-C1 * fpq10(y));
    float o2  = fpq10( C1 * fpq10(z));
    float o3  = fpq10(-C1 * fpq10(x));
    float o4  = fpq10( C2 * fpq10(xy));
    float o5  = fpq10(-C2 * fpq10(yz));
    float o6  = fpq10( C3 * fpq10(z2) - C4);
    float o7  = fpq10(-C2 * fpq10(xz));
    float o8  = fpq10( C5 * fpq10(x2) - C5 * fpq10(y2));
    // triple products: jnp evaluates left-to-right ((qc*qf(a))*qf(b))
    float o9  = fpq10((C6  * fpq10(y)) * fpq10(-3.0f * x2 + y2));
    float o10 = fpq10((C7  * fpq10(xy)) * fpq10(z));
    float o11 = fpq10((C8  * fpq10(y)) * fpq10(1.0f - 5.0f * z2));
    float o12 = fpq10((C9  * fpq10(z)) * fpq10(5.0f * z2 - 3.0f));
    float o13 = fpq10((C8  * fpq10(x)) * fpq10(1.0f - 5.0f * z2));
    float o14 = fpq10((C10 * fpq10(z)) * fpq10(x2 - y2));
    float o15 = fpq10((C6  * fpq10(x)) * fpq10(-x2 + 3.0f * y2));

    float4* op = reinterpret_cast<float4*>(out + (size_t)i * 16);
    op[0] = make_float4(o0,  o1,  o2,  o3);
    op[1] = make_float4(o4,  o5,  o6,  o7);
    op[2] = make_float4(o8,  o9,  o10, o11);
    op[3] = make_float4(o12, o13, o14, o15);
}

extern "C" void kernel_launch(void* const* d_in, const int* in_sizes, int n_in,
                              void* d_out, int out_size, void* d_ws, size_t ws_size,
                              hipStream_t stream) {
    const float* in = (const float*)d_in[0];
    float* out = (float*)d_out;
    int n = in_sizes[0] / 3;           // [N,3] flat
    const int block = 256;
    int grid = (n + block - 1) / block;
    qsh_kernel<<<grid, block, 0, stream>>>(in, out, n);
}

// Round 2
// 288.573 us; speedup vs baseline: 1.0592x; 1.0592x over previous
//
#include <hip/hip_runtime.h>

// Fixed-point quantize to (int_bits=6, frac_bits=10):
// round-half-even to 2^-10 grid, clamp to [-64, 64 - 2^-10].
// rintf == v_rndne_f32 (nearest-even) matches jnp.round semantics.
__device__ __forceinline__ float fpq10(float x) {
    float r = rintf(x * 1024.0f) * 0.0009765625f;  // /1024 exact (pow2)
    r = fmaxf(r, -64.0f);
    r = fminf(r, 63.9990234375f);
    return r;
}

#define PTS 256      // points per block == block size
#define PAD 20       // floats per point in LDS out-staging: 16 + 4 pad
                     // (80 B stride: 16B-aligned for ds_*_b128, breaks pow-2 bank pattern)

__global__ __launch_bounds__(256) void qsh_kernel(const float* __restrict__ in,
                                                  float* __restrict__ out,
                                                  int n) {
    __shared__ float s_in[3 * PTS];        // 3 KB
    __shared__ float s_out[PTS * PAD];     // 20 KB

    const int t = threadIdx.x;
    const long long blockStart = (long long)blockIdx.x * PTS;
    const long long inBase = blockStart * 3;
    const long long nIn = (long long)n * 3;

    // ---- stage input: coalesced global reads (lane stride 4 B) ----
#pragma unroll
    for (int k = 0; k < 3; ++k) {
        long long gi = inBase + k * PTS + t;
        s_in[k * PTS + t] = (gi < nIn) ? in[gi] : 0.0f;
    }
    __syncthreads();

    // per-point values: addresses 3t,3t+1,3t+2 -> 2-way bank aliasing (free)
    float u = s_in[3 * t + 0];
    float v = s_in[3 * t + 1];
    float w = s_in[3 * t + 2];

    // u*2-1 may contract to fma; u*2 is exact so result is bit-identical either way.
    float x = fpq10(u * 2.0f - 1.0f);
    float y = fpq10(v * 2.0f - 1.0f);
    float z = fpq10(w * 2.0f - 1.0f);
    float xy = fpq10(x * y);
    float xz = fpq10(x * z);
    float yz = fpq10(y * z);
    float x2 = fpq10(x * x);
    float y2 = fpq10(y * y);
    float z2 = fpq10(z * z);

    // qc(c) = fpq(float32(c)) precomputed (k/1024 values, hand-verified):
    const float C0  = 0.2822265625f;   // 289/1024
    const float C1  = 0.48828125f;     // 500/1024
    const float C2  = 1.0927734375f;   // 1119/1024
    const float C3  = 0.9462890625f;   // 969/1024
    const float C4  = 0.3154296875f;   // 323/1024
    const float C5  = 0.5458984375f;   // 559/1024
    const float C6  = 0.58984375f;     // 604/1024
    const float C7  = 2.890625f;       // 2960/1024
    const float C8  = 0.45703125f;     // 468/1024
    const float C9  = 0.373046875f;    // 382/1024
    const float C10 = 1.4453125f;      // 1480/1024

    float o0  = C0;
    float o1  = fpq10(-C1 * fpq10(y));
    float o2  = fpq10( C1 * fpq10(z));
    float o3  = fpq10(-C1 * fpq10(x));
    float o4  = fpq10( C2 * fpq10(xy));
    float o5  = fpq10(-C2 * fpq10(yz));
    float o6  = fpq10( C3 * fpq10(z2) - C4);
    float o7  = fpq10(-C2 * fpq10(xz));
    float o8  = fpq10( C5 * fpq10(x2) - C5 * fpq10(y2));
    // triple products: jnp evaluates left-to-right ((qc*qf(a))*qf(b))
    float o9  = fpq10((C6  * fpq10(y)) * fpq10(-3.0f * x2 + y2));
    float o10 = fpq10((C7  * fpq10(xy)) * fpq10(z));
    float o11 = fpq10((C8  * fpq10(y)) * fpq10(1.0f - 5.0f * z2));
    float o12 = fpq10((C9  * fpq10(z)) * fpq10(5.0f * z2 - 3.0f));
    float o13 = fpq10((C8  * fpq10(x)) * fpq10(1.0f - 5.0f * z2));
    float o14 = fpq10((C10 * fpq10(z)) * fpq10(x2 - y2));
    float o15 = fpq10((C6  * fpq10(x)) * fpq10(-x2 + 3.0f * y2));

    // ---- stage output to LDS (padded stride, 16B-aligned per point) ----
    float4* so = reinterpret_cast<float4*>(&s_out[t * PAD]);
    so[0] = make_float4(o0,  o1,  o2,  o3);
    so[1] = make_float4(o4,  o5,  o6,  o7);
    so[2] = make_float4(o8,  o9,  o10, o11);
    so[3] = make_float4(o12, o13, o14, o15);
    __syncthreads();

    // ---- coalesced write-out: 1024 float4s per block, lane stride 16 B ----
    const long long outBase4 = blockStart * 4;        // global float4 index base
    const long long nOut4 = (long long)n * 4;
    float4* outv = reinterpret_cast<float4*>(out);
#pragma unroll
    for (int k = 0; k < 4; ++k) {
        long long f = outBase4 + k * PTS + t;
        if (f < nOut4) {
            int lf = k * PTS + t;                     // local float4 idx 0..1023
            int p = lf >> 2;                          // point within block
            int q = lf & 3;                           // float4 chunk within point
            outv[f] = *reinterpret_cast<const float4*>(&s_out[p * PAD + q * 4]);
        }
    }
}

extern "C" void kernel_launch(void* const* d_in, const int* in_sizes, int n_in,
                              void* d_out, int out_size, void* d_ws, size_t ws_size,
                              hipStream_t stream) {
    const float* in = (const float*)d_in[0];
    float* out = (float*)d_out;
    int n = in_sizes[0] / 3;           // [N,3] flat
    int grid = (n + PTS - 1) / PTS;
    qsh_kernel<<<grid, PTS, 0, stream>>>(in, out, n);
}

// Round 5
// 281.588 us; speedup vs baseline: 1.0855x; 1.0248x over previous
//
#include <hip/hip_runtime.h>

// Fixed-point quantize to (int_bits=6, frac_bits=10):
// round-half-even to 2^-10 grid, clamp to [-64, 64 - 2^-10].
// rintf == v_rndne_f32 (nearest-even) matches jnp.round semantics.
__device__ __forceinline__ float fpq10(float x) {
    float r = rintf(x * 1024.0f) * 0.0009765625f;  // /1024 exact (pow2)
    r = fmaxf(r, -64.0f);
    r = fminf(r, 63.9990234375f);
    return r;
}

#define PTS 256      // points per block == block size
#define PAD 17       // odd stride -> conflict-free b32 LDS writes (gcd(17,32)=1);
                     // total LDS 3+17 KB = 20 KB -> 8 blocks/CU = 32 waves (max occupancy)

__global__ __launch_bounds__(256, 8) void qsh_kernel(const float* __restrict__ in,
                                                     float* __restrict__ out,
                                                     int n) {
    __shared__ float s_in[3 * PTS];        // 3 KB
    __shared__ float s_out[PTS * PAD];     // 17 KB

    const int t = threadIdx.x;
    const long long blockStart = (long long)blockIdx.x * PTS;
    const long long inBase = blockStart * 3;
    const long long nIn = (long long)n * 3;

    // ---- stage input: coalesced global reads (lane stride 4 B) ----
#pragma unroll
    for (int k = 0; k < 3; ++k) {
        long long gi = inBase + k * PTS + t;
        s_in[k * PTS + t] = (gi < nIn) ? in[gi] : 0.0f;
    }
    __syncthreads();

    // per-point values: addresses 3t,3t+1,3t+2 -> 2-way bank aliasing (free)
    float u = s_in[3 * t + 0];
    float v = s_in[3 * t + 1];
    float w = s_in[3 * t + 2];

    // u*2-1 may contract to fma; u*2 is exact so result is bit-identical either way.
    float x = fpq10(u * 2.0f - 1.0f);
    float y = fpq10(v * 2.0f - 1.0f);
    float z = fpq10(w * 2.0f - 1.0f);
    float xy = fpq10(x * y);
    float xz = fpq10(x * z);
    float yz = fpq10(y * z);
    float x2 = fpq10(x * x);
    float y2 = fpq10(y * y);
    float z2 = fpq10(z * z);

    // qc(c) = fpq(float32(c)) precomputed (k/1024 values, hand-verified):
    const float C0  = 0.2822265625f;   // 289/1024
    const float C1  = 0.48828125f;     // 500/1024
    const float C2  = 1.0927734375f;   // 1119/1024
    const float C3  = 0.9462890625f;   // 969/1024
    const float C4  = 0.3154296875f;   // 323/1024
    const float C5  = 0.5458984375f;   // 559/1024
    const float C6  = 0.58984375f;     // 604/1024
    const float C7  = 2.890625f;       // 2960/1024
    const float C8  = 0.45703125f;     // 468/1024
    const float C9  = 0.373046875f;    // 382/1024
    const float C10 = 1.4453125f;      // 1480/1024

    float o0  = C0;
    float o1  = fpq10(-C1 * fpq10(y));
    float o2  = fpq10( C1 * fpq10(z));
    float o3  = fpq10(-C1 * fpq10(x));
    float o4  = fpq10( C2 * fpq10(xy));
    float o5  = fpq10(-C2 * fpq10(yz));
    float o6  = fpq10( C3 * fpq10(z2) - C4);
    float o7  = fpq10(-C2 * fpq10(xz));
    float o8  = fpq10( C5 * fpq10(x2) - C5 * fpq10(y2));
    // triple products: jnp evaluates left-to-right ((qc*qf(a))*qf(b))
    float o9  = fpq10((C6  * fpq10(y)) * fpq10(-3.0f * x2 + y2));
    float o10 = fpq10((C7  * fpq10(xy)) * fpq10(z));
    float o11 = fpq10((C8  * fpq10(y)) * fpq10(1.0f - 5.0f * z2));
    float o12 = fpq10((C9  * fpq10(z)) * fpq10(5.0f * z2 - 3.0f));
    float o13 = fpq10((C8  * fpq10(x)) * fpq10(1.0f - 5.0f * z2));
    float o14 = fpq10((C10 * fpq10(z)) * fpq10(x2 - y2));
    float o15 = fpq10((C6  * fpq10(x)) * fpq10(-x2 + 3.0f * y2));

    // ---- stage output to LDS: 16 b32 writes at odd stride (conflict-free) ----
    float* so = &s_out[t * PAD];
    so[0]  = o0;  so[1]  = o1;  so[2]  = o2;  so[3]  = o3;
    so[4]  = o4;  so[5]  = o5;  so[6]  = o6;  so[7]  = o7;
    so[8]  = o8;  so[9]  = o9;  so[10] = o10; so[11] = o11;
    so[12] = o12; so[13] = o13; so[14] = o14; so[15] = o15;
    __syncthreads();

    // ---- coalesced write-out: 1024 float4s per block, lane stride 16 B ----
    const long long outBase4 = blockStart * 4;        // global float4 index base
    const long long nOut4 = (long long)n * 4;
    float4* outv = reinterpret_cast<float4*>(out);
#pragma unroll
    for (int k = 0; k < 4; ++k) {
        long long f = outBase4 + k * PTS + t;
        if (f < nOut4) {
            int lf = k * PTS + t;                     // local float4 idx 0..1023
            int p = lf >> 2;                          // point within block
            int q = lf & 3;                           // float4 chunk within point
            const float* sp = &s_out[p * PAD + q * 4];
            outv[f] = make_float4(sp[0], sp[1], sp[2], sp[3]);
        }
    }
}

extern "C" void kernel_launch(void* const* d_in, const int* in_sizes, int n_in,
                              void* d_out, int out_size, void* d_ws, size_t ws_size,
                              hipStream_t stream) {
    const float* in = (const float*)d_in[0];
    float* out = (float*)d_out;
    int n = in_sizes[0] / 3;           // [N,3] flat
    int grid = (n + PTS - 1) / PTS;
    qsh_kernel<<<grid, PTS, 0, stream>>>(in, out, n);
}